// Round 3
// baseline (461.102 us; speedup 1.0000x reference)
//
#include <hip/hip_runtime.h>

#define B_ROWS 32768
#define T_BINS 1024
#define M_ROWS 32   // rows per block (R7: was 64; halved to double blocks/CU)

typedef __attribute__((ext_vector_type(8))) _Float16 half8;
typedef __attribute__((ext_vector_type(4))) _Float16 half4v;
typedef __attribute__((ext_vector_type(4))) float floatx4;

__device__ __forceinline__ unsigned long long pack_max(float v, int col) {
    unsigned x = __float_as_uint(v);
    x = (x & 0x80000000u) ? ~x : (x | 0x80000000u);   // monotone float->uint
    return ((unsigned long long)x << 32) | (unsigned)(~col);  // ties -> smaller col
}

__device__ __forceinline__ void async16h(const _Float16* g, _Float16* l) {
    __builtin_amdgcn_global_load_lds(
        (const __attribute__((address_space(1))) unsigned int*)g,
        (__attribute__((address_space(3))) unsigned int*)l,
        16, 0, 0);
}

// ---------------- convert fp32 -> f16 (RNE), used for W only ----------------
__global__ __launch_bounds__(256) void tof16_kernel(
    const float* __restrict__ src, _Float16* __restrict__ dst, int n4)
{
    int idx = blockIdx.x * 256 + threadIdx.x;
    if (idx >= n4) return;
    float4 x = ((const float4*)src)[idx];
    union { _Float16 h[4]; ushort4 u; } cv;
    cv.h[0] = (_Float16)x.x;
    cv.h[1] = (_Float16)x.y;
    cv.h[2] = (_Float16)x.z;
    cv.h[3] = (_Float16)x.w;
    ((ushort4*)dst)[idx] = cv.u;
}

// ---------------- MEGA: GEMM+argmax (full row per block) + loss + scan ----------------
// R7 vs R6 (measured 260us; regression isolated to nontemporal S stores: WRITE_SIZE
// 131->228MB = +44us; GEMM phase unchanged because grid=512 -> 2 blocks/CU grid-limit):
//  (1) M=32 rows/block -> grid 1024 -> 4 blocks/CU -> 16 waves/CU (~45% occ, was 22%).
//      This is the latency-hiding lever the counted-vmcnt needed.
//  (2) Revert nontemporal stores (proven -97MB write inflation).
//  (3) Remove setprio (lockstep barrier GEMM: null-to-negative, m190).
//  (4) Uniform staging: every thread stages 4 halfs of A (8B ds_write) + loads one
//      float4 prefetch; every wave issues 4 W-asyncs -> exactly 5 vmem ops/iter/wave
//      -> vmcnt(5) leaves current iter's 5 in flight, retires previous iter's 5.
//  (5) Keep XOR swizzle (free; conflict counter proved insensitive either way) and
//      per-wave W staging regions (prereq for counted vmcnt).
__global__ __launch_bounds__(256, 4) void mega_kernel(
    const float* __restrict__ A, const _Float16* __restrict__ Wh,
    const float* __restrict__ bias, const float* __restrict__ labels,
    float* __restrict__ out_trunc, float* __restrict__ out_S,
    float* __restrict__ loss_acc)
{
    __shared__ _Float16 sA[2][M_ROWS * 32];   // 2 x 2 KB
    __shared__ _Float16 sW[2][256 * 32];      // 2 x 16 KB
    __shared__ unsigned long long cand[4][M_ROWS];
    __shared__ float trunc_s[M_ROWS];

    const int tid  = threadIdx.x;
    const int lane = tid & 63;
    const int wc   = tid >> 6;      // wave = column group 0..3
    const int by   = blockIdx.x;    // row slab 0..1023

    // ---- A staging: thread -> (row=tid>>3, 4-half chunk c4=tid&7); 8B ds_write,
    //      16B-slot XOR-swizzled: phys slot = (c4>>1) ^ x(row), x(r)=(r^(r>>2))&3
    const int arow = tid >> 3;                 // 0..31
    const int ac4  = tid & 7;                  // 0..7
    const int xr   = (arow ^ (arow >> 2)) & 3;
    const int sAw  = arow * 32 + (((ac4 >> 1) ^ xr) * 8) + (ac4 & 1) * 4;   // halfs
    const float* Abase = A + (size_t)(by * M_ROWS + arow) * T_BINS + ac4 * 4;

    // ---- W staging (per-wave region, linear LDS dest, swizzle folded into global src)
    const int l2    = lane >> 2;
    const int wksw  = ((lane & 3) ^ ((l2 ^ (l2 >> 2)) & 3)) * 8;   // halfs within 32
    const int wcol0 = wc * 64 + l2;

    // ---- fragment reads: k-chunk hi of row/col (..+l15) stored at slot hi^x ----
    const int l15   = lane & 15;
    const int hi    = lane >> 4;
    const int rslot = ((hi ^ ((l15 ^ (l15 >> 2)) & 3)) * 8);       // halfs within 32

    float run_best[2][4];
    int   run_col[2][4];
#pragma unroll
    for (int i = 0; i < 2; ++i)
#pragma unroll
        for (int r = 0; r < 4; ++r) { run_best[i][r] = -3.4e38f; run_col[i][r] = 0; }

    // ---- prologue: stage tile 0 into buf 0; prefetch A regs for tile 1 ----
    {
        float4 f0 = *(const float4*)(Abase);
        half4v hv;
        hv[0] = (_Float16)f0.x; hv[1] = (_Float16)f0.y;
        hv[2] = (_Float16)f0.z; hv[3] = (_Float16)f0.w;
        *(half4v*)&sA[0][sAw] = hv;
    }
#pragma unroll
    for (int r = 0; r < 4; ++r)
        async16h(Wh + (size_t)(wcol0 + r * 16) * T_BINS + wksw,
                 &sW[0][wc * 2048 + r * 512]);
    float4 pa = *(const float4*)(Abase + 32);   // A for tile 1
    asm volatile("s_waitcnt lgkmcnt(0)" ::: "memory");
    __builtin_amdgcn_s_barrier();

    // ---- main loop: 128 tiles (4 bx x 32 k-steps), dbuf, counted vmcnt, no drain ----
    int n = 0;
    for (int bx = 0; bx < 4; ++bx) {
        const int colbase = bx * 256 + wc * 64 + l15;
        float bj[4];
#pragma unroll
        for (int j = 0; j < 4; ++j) bj[j] = bias[colbase + j * 16];

        floatx4 acc[2][4];
#pragma unroll
        for (int i = 0; i < 2; ++i)
#pragma unroll
            for (int j = 0; j < 4; ++j) acc[i][j] = (floatx4){0.f, 0.f, 0.f, 0.f};

        for (int t = 0; t < 32; ++t, ++n) {
            const int cur = n & 1;
            const int nxt = cur ^ 1;
            const int m   = (n + 1) & 127;   // next tile (wrap at end harmless)
            const int bxn = m >> 5;
            const int k0n = (m & 31) * 32;

            // 1. prefetch A regs for tile n+2 (A depends only on k)
            const int kq = ((n + 2) & 31) * 32;
            float4 qa = *(const float4*)(Abase + kq);

            // 2. stage W(n+1) into the other buffer (this wave's own read region)
#pragma unroll
            for (int r = 0; r < 4; ++r)
                async16h(Wh + (size_t)(bxn * 256 + wcol0 + r * 16) * T_BINS + k0n + wksw,
                         &sW[nxt][wc * 2048 + r * 512]);

            // 3. stage A(n+1) from regs into the other buffer (swizzled slot)
            {
                half4v hv;
                hv[0] = (_Float16)pa.x; hv[1] = (_Float16)pa.y;
                hv[2] = (_Float16)pa.z; hv[3] = (_Float16)pa.w;
                *(half4v*)&sA[nxt][sAw] = hv;
            }
            pa = qa;

            // 4. counted wait: the 5 newest vmem ops (1 qa + 4 W(n+1)) stay in flight;
            //    everything older -- incl. this wave's W(cur) from last iter -- is done.
            asm volatile("s_waitcnt vmcnt(5)" ::: "memory");

            half8 ah[2], whf[4];
#pragma unroll
            for (int i = 0; i < 2; ++i)
                ah[i] = *(const half8*)&sA[cur][(i * 16 + l15) * 32 + rslot];
#pragma unroll
            for (int j = 0; j < 4; ++j)
                whf[j] = *(const half8*)&sW[cur][(wc * 64 + j * 16 + l15) * 32 + rslot];

#pragma unroll
            for (int i = 0; i < 2; ++i)
#pragma unroll
                for (int j = 0; j < 4; ++j)
                    acc[i][j] = __builtin_amdgcn_mfma_f32_16x16x32_f16(ah[i], whf[j], acc[i][j], 0, 0, 0);

            // 5. barrier guards the cross-wave sA ds_write + buffer swap; NO vmcnt drain.
            asm volatile("s_waitcnt lgkmcnt(0)" ::: "memory");
            __builtin_amdgcn_s_barrier();
        }

        // fold this bx's acc into the running argmax (cols strictly increase)
#pragma unroll
        for (int i = 0; i < 2; ++i)
#pragma unroll
            for (int r = 0; r < 4; ++r)
#pragma unroll
                for (int j = 0; j < 4; ++j) {
                    float v = acc[i][j][r] + bj[j];
                    if (v > run_best[i][r]) { run_best[i][r] = v; run_col[i][r] = colbase + j * 16; }
                }
    }

    // 16-lane (column-lane) reduce; lanes {0,16,32,48} publish per-row candidates
#pragma unroll
    for (int i = 0; i < 2; ++i)
#pragma unroll
        for (int r = 0; r < 4; ++r) {
            float best = run_best[i][r];
            int   bc   = run_col[i][r];
#pragma unroll
            for (int off = 8; off >= 1; off >>= 1) {
                float ov = __shfl_xor(best, off, 64);
                int   oc = __shfl_xor(bc, off, 64);
                if (ov > best || (ov == best && oc < bc)) { best = ov; bc = oc; }
            }
            if ((lane & 15) == 0)
                cand[wc][i * 16 + (lane >> 4) * 4 + r] = pack_max(best, bc);
        }
    __syncthreads();   // full drain once (also retires the wrapped last-iter prefetches)

    // wave 0: combine 4 col-group candidates per row, write trunc_pos + loss
    if (tid < M_ROWS) {
        unsigned long long m01 = cand[0][tid] > cand[1][tid] ? cand[0][tid] : cand[1][tid];
        unsigned long long m23 = cand[2][tid] > cand[3][tid] ? cand[2][tid] : cand[3][tid];
        unsigned long long mm = m01 > m23 ? m01 : m23;
        unsigned col = ~(unsigned)mm;
        float p = (float)col;
        int rowG = by * M_ROWS + tid;
        out_trunc[rowG] = p;
        trunc_s[tid] = p;
        float d = p - labels[rowG];
        float term = d * d * (1.0f / (float)B_ROWS);
        // 32 active lanes (all in wave 0): offsets 16..1; lanes >=16 get garbage from
        // inactive lanes at off=16 but their values are never consumed afterwards.
#pragma unroll
        for (int off = 16; off >= 1; off >>= 1)
            term += __shfl_down(term, off, 64);
        if (tid == 0) atomicAdd(loss_acc, term);
    }
    __syncthreads();

    // scan phase: wave wc handles rows wc*8 .. wc*8+7; lane covers 16 elements
    for (int rr = 0; rr < 8; ++rr) {
        int row  = wc * 8 + rr;
        int rowG = by * M_ROWS + row;
        const float* Hrow = A + (size_t)rowG * T_BINS + lane * 16;
        float4 h0 = *(const float4*)(Hrow + 0);
        float4 h1 = *(const float4*)(Hrow + 4);
        float4 h2 = *(const float4*)(Hrow + 8);
        float4 h3 = *(const float4*)(Hrow + 12);
        float hv[16] = {h0.x, h0.y, h0.z, h0.w, h1.x, h1.y, h1.z, h1.w,
                        h2.x, h2.y, h2.z, h2.w, h3.x, h3.y, h3.z, h3.w};
        float vprod[16];
        float run = 1.f;
#pragma unroll
        for (int j = 0; j < 16; ++j) { run *= (1.f - hv[j]); vprod[j] = run; }
        float x = run;
#pragma unroll
        for (int off = 1; off < 64; off <<= 1) {
            float o = __shfl_up(x, off, 64);
            if (lane >= off) x *= o;
        }
        float pre = __shfl_up(x, 1, 64);
        if (lane == 0) pre = 1.f;

        int p  = (int)trunc_s[row];
        int t0 = lane * 16;
        float sv[16];
#pragma unroll
        for (int j = 0; j < 16; ++j) {
            float s = pre * vprod[j];
            int t = t0 + j;
            if (t >= p) s *= __expf((float)(p - t));
            sv[j] = s;
        }
        float* Srow = out_S + (size_t)rowG * T_BINS + lane * 16;
        *(float4*)(Srow + 0)  = (float4){sv[0],  sv[1],  sv[2],  sv[3]};
        *(float4*)(Srow + 4)  = (float4){sv[4],  sv[5],  sv[6],  sv[7]};
        *(float4*)(Srow + 8)  = (float4){sv[8],  sv[9],  sv[10], sv[11]};
        *(float4*)(Srow + 12) = (float4){sv[12], sv[13], sv[14], sv[15]};
    }
}

// ---------------- fp32 fallback path (round-1 kernels), used if ws too small ----------------
#define BMf 64
#define BKf 16
#define LDSS (BMf + 4)
__global__ __launch_bounds__(256) void gemm_argmax_fp32(
    const float* __restrict__ A, const float* __restrict__ W,
    const float* __restrict__ bias, unsigned long long* __restrict__ rec)
{
    __shared__ float As[BKf][LDSS];
    __shared__ float Ws[BKf][LDSS];
    const int tid = threadIdx.x;
    const int tx = tid & 15, ty = tid >> 4;
    const int bx = blockIdx.x, by = blockIdx.y;
    const int ar = tid >> 2, ak = (tid & 3) << 2;
    const float* Arow = A + (size_t)(by * BMf + ar) * T_BINS + ak;
    const float* Wrow = W + (size_t)(bx * BMf + ar) * T_BINS + ak;
    float acc[4][4];
#pragma unroll
    for (int i = 0; i < 4; ++i)
#pragma unroll
        for (int j = 0; j < 4; ++j) acc[i][j] = 0.f;
    for (int k0 = 0; k0 < T_BINS; k0 += BKf) {
        float4 av = *(const float4*)(Arow + k0);
        float4 wvv = *(const float4*)(Wrow + k0);
        As[ak + 0][ar] = av.x; As[ak + 1][ar] = av.y; As[ak + 2][ar] = av.z; As[ak + 3][ar] = av.w;
        Ws[ak + 0][ar] = wvv.x; Ws[ak + 1][ar] = wvv.y; Ws[ak + 2][ar] = wvv.z; Ws[ak + 3][ar] = wvv.w;
        __syncthreads();
#pragma unroll
        for (int k = 0; k < BKf; ++k) {
            float4 a4 = *(const float4*)&As[k][ty * 4];
            float4 w4 = *(const float4*)&Ws[k][tx * 4];
            float aa[4] = {a4.x, a4.y, a4.z, a4.w};
            float ww[4] = {w4.x, w4.y, w4.z, w4.w};
#pragma unroll
            for (int i = 0; i < 4; ++i)
#pragma unroll
                for (int j = 0; j < 4; ++j) acc[i][j] = fmaf(aa[i], ww[j], acc[i][j]);
        }
        __syncthreads();
    }
    const int colBase = bx * BMf + tx * 4;
    float bv[4];
#pragma unroll
    for (int j = 0; j < 4; ++j) bv[j] = bias[colBase + j];
#pragma unroll
    for (int i = 0; i < 4; ++i) {
        float best = acc[i][0] + bv[0];
        int bc = colBase;
#pragma unroll
        for (int j = 1; j < 4; ++j) {
            float v = acc[i][j] + bv[j];
            if (v > best) { best = v; bc = colBase + j; }
        }
#pragma unroll
        for (int off = 8; off >= 1; off >>= 1) {
            float ov = __shfl_xor(best, off, 64);
            int oc = __shfl_xor(bc, off, 64);
            if (ov > best || (ov == best && oc < bc)) { best = ov; bc = oc; }
        }
        if (tx == 0) atomicMax(&rec[by * BMf + ty * 4 + i], pack_max(best, bc));
    }
}

__global__ __launch_bounds__(256) void finalize_kernel(
    const unsigned long long* __restrict__ rec, const float* __restrict__ labels,
    float* __restrict__ out_trunc, float* __restrict__ loss_acc)
{
    int i = blockIdx.x * 256 + threadIdx.x;
    unsigned col = ~(unsigned)(rec[i] & 0xFFFFFFFFull);
    float p = (float)col;
    out_trunc[i] = p;
    float d = p - labels[i];
    float term = d * d * (1.0f / (float)B_ROWS);
#pragma unroll
    for (int off = 32; off >= 1; off >>= 1)
        term += __shfl_down(term, off, 64);
    __shared__ float partials[4];
    int lane = threadIdx.x & 63, wv = threadIdx.x >> 6;
    if (lane == 0) partials[wv] = term;
    __syncthreads();
    if (threadIdx.x == 0)
        atomicAdd(loss_acc, partials[0] + partials[1] + partials[2] + partials[3]);
}

__global__ __launch_bounds__(256) void scan_kernel_f32(
    const float* __restrict__ H, const float* __restrict__ trunc_f,
    float* __restrict__ Sout)
{
    const int row = blockIdx.x;
    const int tid = threadIdx.x;
    const int lane = tid & 63;
    const int wv = tid >> 6;
    const float4 h = *(const float4*)(H + (size_t)row * T_BINS + tid * 4);
    float l0 = 1.f - h.x;
    float l1 = l0 * (1.f - h.y);
    float l2 = l1 * (1.f - h.z);
    float l3 = l2 * (1.f - h.w);
    float x = l3;
#pragma unroll
    for (int off = 1; off < 64; off <<= 1) {
        float o = __shfl_up(x, off, 64);
        if (lane >= off) x *= o;
    }
    float ex = __shfl_up(x, 1, 64);
    if (lane == 0) ex = 1.f;
    __shared__ float wtot[4];
    if (lane == 63) wtot[wv] = x;
    __syncthreads();
    float wpre = 1.f;
#pragma unroll
    for (int w = 0; w < 3; ++w)
        if (w < wv) wpre *= wtot[w];
    float pre = wpre * ex;
    int p = (int)trunc_f[row];
    int t0 = tid * 4;
    float sv[4] = {pre * l0, pre * l1, pre * l2, pre * l3};
#pragma unroll
    for (int j = 0; j < 4; ++j) {
        int t = t0 + j;
        if (t >= p) sv[j] *= __expf((float)(p - t));
    }
    float4 s4 = {sv[0], sv[1], sv[2], sv[3]};
    *(float4*)(Sout + (size_t)row * T_BINS + tid * 4) = s4;
}

extern "C" void kernel_launch(void* const* d_in, const int* in_sizes, int n_in,
                              void* d_out, int out_size, void* d_ws, size_t ws_size,
                              hipStream_t stream)
{
    const float* hazard = (const float*)d_in[0];   // [B, T]
    const float* labels = (const float*)d_in[1];   // [B]
    const float* W      = (const float*)d_in[2];   // [T, T]
    const float* bias   = (const float*)d_in[3];   // [T]

    float* out       = (float*)d_out;
    float* out_trunc = out;                                       // B floats
    float* out_S     = out + B_ROWS;                              // B*T floats
    float* out_loss  = out + B_ROWS + (size_t)B_ROWS * T_BINS;    // 1 float

    hipMemsetAsync(out_loss, 0, sizeof(float), stream);

    const size_t NW = (size_t)T_BINS * T_BINS;
    if (ws_size >= NW * sizeof(_Float16)) {
        _Float16* Wh = (_Float16*)d_ws;
        tof16_kernel<<<(int)(NW / 4 / 256), 256, 0, stream>>>(W, Wh, (int)(NW / 4));
        mega_kernel<<<B_ROWS / M_ROWS, 256, 0, stream>>>(
            hazard, Wh, bias, labels, out_trunc, out_S, out_loss);
    } else {
        unsigned long long* rec = (unsigned long long*)out_S;
        hipMemsetAsync(rec, 0, (size_t)B_ROWS * sizeof(unsigned long long), stream);
        dim3 ggrid(T_BINS / BMf, B_ROWS / BMf);
        gemm_argmax_fp32<<<ggrid, 256, 0, stream>>>(hazard, W, bias, rec);
        finalize_kernel<<<B_ROWS / 256, 256, 0, stream>>>(rec, labels, out_trunc, out_loss);
        scan_kernel_f32<<<B_ROWS, 256, 0, stream>>>(hazard, out_trunc, out_S);
    }
}

// Round 4
// 352.793 us; speedup vs baseline: 1.3070x; 1.3070x over previous
//
#include <hip/hip_runtime.h>

#define B_ROWS 32768
#define T_BINS 1024

typedef __attribute__((ext_vector_type(8))) _Float16 half8;
typedef __attribute__((ext_vector_type(4))) float floatx4;

__device__ __forceinline__ unsigned long long pack_max(float v, int col) {
    unsigned x = __float_as_uint(v);
    x = (x & 0x80000000u) ? ~x : (x | 0x80000000u);   // monotone float->uint
    return ((unsigned long long)x << 32) | (unsigned)(~col);  // ties -> smaller col
}

__device__ __forceinline__ void async16h(const _Float16* g, _Float16* l) {
    __builtin_amdgcn_global_load_lds(
        (const __attribute__((address_space(1))) unsigned int*)g,
        (__attribute__((address_space(3))) unsigned int*)l,
        16, 0, 0);
}

// ---------------- convert fp32 -> f16 (RNE), used for W only ----------------
__global__ __launch_bounds__(256) void tof16_kernel(
    const float* __restrict__ src, _Float16* __restrict__ dst, int n4)
{
    int idx = blockIdx.x * 256 + threadIdx.x;
    if (idx >= n4) return;
    float4 x = ((const float4*)src)[idx];
    union { _Float16 h[4]; ushort4 u; } cv;
    cv.h[0] = (_Float16)x.x;
    cv.h[1] = (_Float16)x.y;
    cv.h[2] = (_Float16)x.z;
    cv.h[3] = (_Float16)x.w;
    ((ushort4*)dst)[idx] = cv.u;
}

// ---------------- MEGA: GEMM+argmax (full row per block) + loss + scan ----------------
// R8 vs R7 (304us) / R4 (218us baseline):
//  Evidence: per-iter GEMM cost is ~constant (latency/barrier-chain bound) — R7 halved
//  per-iter MFMA work and occupancy 2x'd, yet per-iter time ROSE. Counted vmcnt was
//  neutral (compiler inserts its own waits for global_load_lds->ds_read aliasing).
//  Lever: fewer, fatter iterations. M=64 (R4 geometry, best measured) + BK=64:
//   - 64 K-iterations (was 128); 32 MFMA/wave/iter (was 16); 40KB staged/iter.
//   - LDS 80KB/block: free (grid=512 -> 2 blocks/CU regardless; 160/80=2).
//   - 8-slot XOR swizzle x8(r)=(r^(r>>3))&7 on 16B slots -> 2-way (free) frag reads.
//   - plain __syncthreads (counted vmcnt proven neutral); no setprio; no nontemporal.
//   - cand/trunc_s overlaid on dead sA after the K-loop to stay at 80KB.
__global__ __launch_bounds__(256, 2) void mega_kernel(
    const float* __restrict__ A, const _Float16* __restrict__ Wh,
    const float* __restrict__ bias, const float* __restrict__ labels,
    float* __restrict__ out_trunc, float* __restrict__ out_S,
    float* __restrict__ loss_acc)
{
    __shared__ _Float16 sA[2][64 * 64];      // 16 KB
    __shared__ _Float16 sW[2][256 * 64];     // 64 KB

    const int tid  = threadIdx.x;
    const int lane = tid & 63;
    const int wc   = tid >> 6;      // wave = column group 0..3
    const int by   = blockIdx.x;    // row slab 0..511

    // ---- A staging: thread -> (row=tid>>2, 16-float chunk ac=tid&3) -> two half8
    //      ds_writes at 16B slots (2ac)^x8(row), (2ac+1)^x8(row), x8(r)=(r^(r>>3))&7
    const int arow = tid >> 2;                 // 0..63
    const int ac   = tid & 3;                  // 0..3
    const int x8a  = (arow ^ (arow >> 3)) & 7;
    const int sAw0 = arow * 64 + (((ac * 2) ^ x8a) * 8);       // halfs
    const int sAw1 = arow * 64 + (((ac * 2 + 1) ^ x8a) * 8);   // halfs
    const float* Abase = A + (size_t)(by * 64 + arow) * T_BINS + ac * 16;

    // ---- W staging: 8 asyncs/wave; async r covers cols wc*64+r*8 .. +8 (8 cols x 8
    //      slots, lane l -> col+(l>>3), phys slot l&7); swizzle folded into global src:
    //      src k-chunk = (l&7) ^ (l>>3) ^ r   [since x8(col) = (l>>3) ^ r]
    const int l3   = lane >> 3;    // 0..7
    const int wsl  = lane & 7;     // 0..7

    // ---- fragment reads: logical slot g*4+hi -> phys (g*4+hi) ^ xc ^ (i*2 or j*2)
    const int l15  = lane & 15;
    const int hi   = lane >> 4;
    const int xc   = (l15 & 7) ^ (l15 >> 3);

    float run_best[4][4];
    int   run_col[4][4];
#pragma unroll
    for (int i = 0; i < 4; ++i)
#pragma unroll
        for (int r = 0; r < 4; ++r) { run_best[i][r] = -3.4e38f; run_col[i][r] = 0; }

    // ---- prologue: stage tile 0 into buf 0; prefetch A regs for tile 1 ----
    {
        float4 f0 = *(const float4*)(Abase + 0);
        float4 f1 = *(const float4*)(Abase + 4);
        float4 f2 = *(const float4*)(Abase + 8);
        float4 f3 = *(const float4*)(Abase + 12);
        half8 h0, h1;
        h0[0] = (_Float16)f0.x; h0[1] = (_Float16)f0.y; h0[2] = (_Float16)f0.z; h0[3] = (_Float16)f0.w;
        h0[4] = (_Float16)f1.x; h0[5] = (_Float16)f1.y; h0[6] = (_Float16)f1.z; h0[7] = (_Float16)f1.w;
        h1[0] = (_Float16)f2.x; h1[1] = (_Float16)f2.y; h1[2] = (_Float16)f2.z; h1[3] = (_Float16)f2.w;
        h1[4] = (_Float16)f3.x; h1[5] = (_Float16)f3.y; h1[6] = (_Float16)f3.z; h1[7] = (_Float16)f3.w;
        *(half8*)&sA[0][sAw0] = h0;
        *(half8*)&sA[0][sAw1] = h1;
    }
#pragma unroll
    for (int r = 0; r < 8; ++r)
        async16h(Wh + (size_t)(wc * 64 + r * 8 + l3) * T_BINS + ((wsl ^ l3 ^ r) * 8),
                 &sW[0][(wc * 64 + r * 8) * 64]);
    float4 pa0 = *(const float4*)(Abase + 64);
    float4 pa1 = *(const float4*)(Abase + 68);
    float4 pa2 = *(const float4*)(Abase + 72);
    float4 pa3 = *(const float4*)(Abase + 76);
    __syncthreads();

    // ---- main loop: 64 tiles (4 bx x 16 k-steps of BK=64), double-buffered ----
    int n = 0;
    for (int bx = 0; bx < 4; ++bx) {
        const int colbase = bx * 256 + wc * 64 + l15;
        float bj[4];
#pragma unroll
        for (int j = 0; j < 4; ++j) bj[j] = bias[colbase + j * 16];

        floatx4 acc[4][4];
#pragma unroll
        for (int i = 0; i < 4; ++i)
#pragma unroll
            for (int j = 0; j < 4; ++j) acc[i][j] = (floatx4){0.f, 0.f, 0.f, 0.f};

        for (int t = 0; t < 16; ++t, ++n) {
            const int cur = n & 1;
            const int nxt = cur ^ 1;
            const int m   = (n + 1) & 63;    // next tile (wrap at end harmless)
            const int bxn = m >> 4;
            const int k0n = (m & 15) * 64;

            // 1. prefetch A regs for tile n+2 (A depends only on k)
            const int kq = ((n + 2) & 15) * 64;
            float4 qa0 = *(const float4*)(Abase + kq + 0);
            float4 qa1 = *(const float4*)(Abase + kq + 4);
            float4 qa2 = *(const float4*)(Abase + kq + 8);
            float4 qa3 = *(const float4*)(Abase + kq + 12);

            // 2. stage W(n+1) into the other buffer (this wave's own read region)
#pragma unroll
            for (int r = 0; r < 8; ++r)
                async16h(Wh + (size_t)(bxn * 256 + wc * 64 + r * 8 + l3) * T_BINS
                            + k0n + ((wsl ^ l3 ^ r) * 8),
                         &sW[nxt][(wc * 64 + r * 8) * 64]);

            // 3. stage A(n+1) from regs into the other buffer (swizzled slots)
            {
                half8 h0, h1;
                h0[0] = (_Float16)pa0.x; h0[1] = (_Float16)pa0.y; h0[2] = (_Float16)pa0.z; h0[3] = (_Float16)pa0.w;
                h0[4] = (_Float16)pa1.x; h0[5] = (_Float16)pa1.y; h0[6] = (_Float16)pa1.z; h0[7] = (_Float16)pa1.w;
                h1[0] = (_Float16)pa2.x; h1[1] = (_Float16)pa2.y; h1[2] = (_Float16)pa2.z; h1[3] = (_Float16)pa2.w;
                h1[4] = (_Float16)pa3.x; h1[5] = (_Float16)pa3.y; h1[6] = (_Float16)pa3.z; h1[7] = (_Float16)pa3.w;
                *(half8*)&sA[nxt][sAw0] = h0;
                *(half8*)&sA[nxt][sAw1] = h1;
            }
            pa0 = qa0; pa1 = qa1; pa2 = qa2; pa3 = qa3;

            // 4. fragments + MFMA on current buffers: 2 k-subtiles x 16 MFMA
#pragma unroll
            for (int g = 0; g < 2; ++g) {
                half8 ah[4], whf[4];
#pragma unroll
                for (int i = 0; i < 4; ++i)
                    ah[i] = *(const half8*)&sA[cur][(i * 16 + l15) * 64
                                                    + (((g * 4 + hi) ^ xc ^ (i * 2)) * 8)];
#pragma unroll
                for (int j = 0; j < 4; ++j)
                    whf[j] = *(const half8*)&sW[cur][(wc * 64 + j * 16 + l15) * 64
                                                     + (((g * 4 + hi) ^ xc ^ (j * 2)) * 8)];
#pragma unroll
                for (int i = 0; i < 4; ++i)
#pragma unroll
                    for (int j = 0; j < 4; ++j)
                        acc[i][j] = __builtin_amdgcn_mfma_f32_16x16x32_f16(ah[i], whf[j], acc[i][j], 0, 0, 0);
            }

            // 5. barrier: guards buffer swap (drains asyncs + ds_writes + prefetches)
            __syncthreads();
        }

        // fold this bx's acc into the running argmax (cols strictly increase)
#pragma unroll
        for (int i = 0; i < 4; ++i)
#pragma unroll
            for (int r = 0; r < 4; ++r)
#pragma unroll
                for (int j = 0; j < 4; ++j) {
                    float v = acc[i][j][r] + bj[j];
                    if (v > run_best[i][r]) { run_best[i][r] = v; run_col[i][r] = colbase + j * 16; }
                }
    }

    // ---- epilogue: cand/trunc overlaid on dead sA (keeps LDS at 80KB) ----
    unsigned long long (*cand)[64] = reinterpret_cast<unsigned long long (*)[64]>(&sA[0][0]);
    float* trunc_s = reinterpret_cast<float*>(&sA[0][0]) + 512;   // bytes 2048..2303

    // 16-lane (column-lane) reduce; lanes {0,16,32,48} publish per-row candidates
#pragma unroll
    for (int i = 0; i < 4; ++i)
#pragma unroll
        for (int r = 0; r < 4; ++r) {
            float best = run_best[i][r];
            int   bc   = run_col[i][r];
#pragma unroll
            for (int off = 8; off >= 1; off >>= 1) {
                float ov = __shfl_xor(best, off, 64);
                int   oc = __shfl_xor(bc, off, 64);
                if (ov > best || (ov == best && oc < bc)) { best = ov; bc = oc; }
            }
            if ((lane & 15) == 0)
                cand[wc][i * 16 + (lane >> 4) * 4 + r] = pack_max(best, bc);
        }
    __syncthreads();

    // wave 0: combine 4 col-group candidates per row, write trunc_pos + loss
    if (tid < 64) {
        unsigned long long m01 = cand[0][tid] > cand[1][tid] ? cand[0][tid] : cand[1][tid];
        unsigned long long m23 = cand[2][tid] > cand[3][tid] ? cand[2][tid] : cand[3][tid];
        unsigned long long mm = m01 > m23 ? m01 : m23;
        unsigned col = ~(unsigned)mm;
        float p = (float)col;
        int rowG = by * 64 + tid;
        out_trunc[rowG] = p;
        trunc_s[tid] = p;
        float d = p - labels[rowG];
        float term = d * d * (1.0f / (float)B_ROWS);
#pragma unroll
        for (int off = 32; off >= 1; off >>= 1)
            term += __shfl_down(term, off, 64);
        if (tid == 0) atomicAdd(loss_acc, term);
    }
    __syncthreads();

    // scan phase: wave wc handles rows wc*16 .. wc*16+15; lane covers 16 elements
    for (int rr = 0; rr < 16; ++rr) {
        int row  = wc * 16 + rr;
        int rowG = by * 64 + row;
        const float* Hrow = A + (size_t)rowG * T_BINS + lane * 16;
        float4 h0 = *(const float4*)(Hrow + 0);
        float4 h1 = *(const float4*)(Hrow + 4);
        float4 h2 = *(const float4*)(Hrow + 8);
        float4 h3 = *(const float4*)(Hrow + 12);
        float hv[16] = {h0.x, h0.y, h0.z, h0.w, h1.x, h1.y, h1.z, h1.w,
                        h2.x, h2.y, h2.z, h2.w, h3.x, h3.y, h3.z, h3.w};
        float vprod[16];
        float run = 1.f;
#pragma unroll
        for (int j = 0; j < 16; ++j) { run *= (1.f - hv[j]); vprod[j] = run; }
        float x = run;
#pragma unroll
        for (int off = 1; off < 64; off <<= 1) {
            float o = __shfl_up(x, off, 64);
            if (lane >= off) x *= o;
        }
        float pre = __shfl_up(x, 1, 64);
        if (lane == 0) pre = 1.f;

        int p  = (int)trunc_s[row];
        int t0 = lane * 16;
        float sv[16];
#pragma unroll
        for (int j = 0; j < 16; ++j) {
            float s = pre * vprod[j];
            int t = t0 + j;
            if (t >= p) s *= __expf((float)(p - t));
            sv[j] = s;
        }
        float* Srow = out_S + (size_t)rowG * T_BINS + lane * 16;
        *(float4*)(Srow + 0)  = (float4){sv[0],  sv[1],  sv[2],  sv[3]};
        *(float4*)(Srow + 4)  = (float4){sv[4],  sv[5],  sv[6],  sv[7]};
        *(float4*)(Srow + 8)  = (float4){sv[8],  sv[9],  sv[10], sv[11]};
        *(float4*)(Srow + 12) = (float4){sv[12], sv[13], sv[14], sv[15]};
    }
}

// ---------------- fp32 fallback path (round-1 kernels), used if ws too small ----------------
#define BMf 64
#define BKf 16
#define LDSS (BMf + 4)
__global__ __launch_bounds__(256) void gemm_argmax_fp32(
    const float* __restrict__ A, const float* __restrict__ W,
    const float* __restrict__ bias, unsigned long long* __restrict__ rec)
{
    __shared__ float As[BKf][LDSS];
    __shared__ float Ws[BKf][LDSS];
    const int tid = threadIdx.x;
    const int tx = tid & 15, ty = tid >> 4;
    const int bx = blockIdx.x, by = blockIdx.y;
    const int ar = tid >> 2, ak = (tid & 3) << 2;
    const float* Arow = A + (size_t)(by * BMf + ar) * T_BINS + ak;
    const float* Wrow = W + (size_t)(bx * BMf + ar) * T_BINS + ak;
    float acc[4][4];
#pragma unroll
    for (int i = 0; i < 4; ++i)
#pragma unroll
        for (int j = 0; j < 4; ++j) acc[i][j] = 0.f;
    for (int k0 = 0; k0 < T_BINS; k0 += BKf) {
        float4 av = *(const float4*)(Arow + k0);
        float4 wvv = *(const float4*)(Wrow + k0);
        As[ak + 0][ar] = av.x; As[ak + 1][ar] = av.y; As[ak + 2][ar] = av.z; As[ak + 3][ar] = av.w;
        Ws[ak + 0][ar] = wvv.x; Ws[ak + 1][ar] = wvv.y; Ws[ak + 2][ar] = wvv.z; Ws[ak + 3][ar] = wvv.w;
        __syncthreads();
#pragma unroll
        for (int k = 0; k < BKf; ++k) {
            float4 a4 = *(const float4*)&As[k][ty * 4];
            float4 w4 = *(const float4*)&Ws[k][tx * 4];
            float aa[4] = {a4.x, a4.y, a4.z, a4.w};
            float ww[4] = {w4.x, w4.y, w4.z, w4.w};
#pragma unroll
            for (int i = 0; i < 4; ++i)
#pragma unroll
                for (int j = 0; j < 4; ++j) acc[i][j] = fmaf(aa[i], ww[j], acc[i][j]);
        }
        __syncthreads();
    }
    const int colBase = bx * BMf + tx * 4;
    float bv[4];
#pragma unroll
    for (int j = 0; j < 4; ++j) bv[j] = bias[colBase + j];
#pragma unroll
    for (int i = 0; i < 4; ++i) {
        float best = acc[i][0] + bv[0];
        int bc = colBase;
#pragma unroll
        for (int j = 1; j < 4; ++j) {
            float v = acc[i][j] + bv[j];
            if (v > best) { best = v; bc = colBase + j; }
        }
#pragma unroll
        for (int off = 8; off >= 1; off >>= 1) {
            float ov = __shfl_xor(best, off, 64);
            int oc = __shfl_xor(bc, off, 64);
            if (ov > best || (ov == best && oc < bc)) { best = ov; bc = oc; }
        }
        if (tx == 0) atomicMax(&rec[by * BMf + ty * 4 + i], pack_max(best, bc));
    }
}

__global__ __launch_bounds__(256) void finalize_kernel(
    const unsigned long long* __restrict__ rec, const float* __restrict__ labels,
    float* __restrict__ out_trunc, float* __restrict__ loss_acc)
{
    int i = blockIdx.x * 256 + threadIdx.x;
    unsigned col = ~(unsigned)(rec[i] & 0xFFFFFFFFull);
    float p = (float)col;
    out_trunc[i] = p;
    float d = p - labels[i];
    float term = d * d * (1.0f / (float)B_ROWS);
#pragma unroll
    for (int off = 32; off >= 1; off >>= 1)
        term += __shfl_down(term, off, 64);
    __shared__ float partials[4];
    int lane = threadIdx.x & 63, wv = threadIdx.x >> 6;
    if (lane == 0) partials[wv] = term;
    __syncthreads();
    if (threadIdx.x == 0)
        atomicAdd(loss_acc, partials[0] + partials[1] + partials[2] + partials[3]);
}

__global__ __launch_bounds__(256) void scan_kernel_f32(
    const float* __restrict__ H, const float* __restrict__ trunc_f,
    float* __restrict__ Sout)
{
    const int row = blockIdx.x;
    const int tid = threadIdx.x;
    const int lane = tid & 63;
    const int wv = tid >> 6;
    const float4 h = *(const float4*)(H + (size_t)row * T_BINS + tid * 4);
    float l0 = 1.f - h.x;
    float l1 = l0 * (1.f - h.y);
    float l2 = l1 * (1.f - h.z);
    float l3 = l2 * (1.f - h.w);
    float x = l3;
#pragma unroll
    for (int off = 1; off < 64; off <<= 1) {
        float o = __shfl_up(x, off, 64);
        if (lane >= off) x *= o;
    }
    float ex = __shfl_up(x, 1, 64);
    if (lane == 0) ex = 1.f;
    __shared__ float wtot[4];
    if (lane == 63) wtot[wv] = x;
    __syncthreads();
    float wpre = 1.f;
#pragma unroll
    for (int w = 0; w < 3; ++w)
        if (w < wv) wpre *= wtot[w];
    float pre = wpre * ex;
    int p = (int)trunc_f[row];
    int t0 = tid * 4;
    float sv[4] = {pre * l0, pre * l1, pre * l2, pre * l3};
#pragma unroll
    for (int j = 0; j < 4; ++j) {
        int t = t0 + j;
        if (t >= p) sv[j] *= __expf((float)(p - t));
    }
    float4 s4 = {sv[0], sv[1], sv[2], sv[3]};
    *(float4*)(Sout + (size_t)row * T_BINS + tid * 4) = s4;
}

extern "C" void kernel_launch(void* const* d_in, const int* in_sizes, int n_in,
                              void* d_out, int out_size, void* d_ws, size_t ws_size,
                              hipStream_t stream)
{
    const float* hazard = (const float*)d_in[0];   // [B, T]
    const float* labels = (const float*)d_in[1];   // [B]
    const float* W      = (const float*)d_in[2];   // [T, T]
    const float* bias   = (const float*)d_in[3];   // [T]

    float* out       = (float*)d_out;
    float* out_trunc = out;                                       // B floats
    float* out_S     = out + B_ROWS;                              // B*T floats
    float* out_loss  = out + B_ROWS + (size_t)B_ROWS * T_BINS;    // 1 float

    hipMemsetAsync(out_loss, 0, sizeof(float), stream);

    const size_t NW = (size_t)T_BINS * T_BINS;
    if (ws_size >= NW * sizeof(_Float16)) {
        _Float16* Wh = (_Float16*)d_ws;
        tof16_kernel<<<(int)(NW / 4 / 256), 256, 0, stream>>>(W, Wh, (int)(NW / 4));
        mega_kernel<<<B_ROWS / 64, 256, 0, stream>>>(
            hazard, Wh, bias, labels, out_trunc, out_S, out_loss);
    } else {
        unsigned long long* rec = (unsigned long long*)out_S;
        hipMemsetAsync(rec, 0, (size_t)B_ROWS * sizeof(unsigned long long), stream);
        dim3 ggrid(T_BINS / BMf, B_ROWS / BMf);
        gemm_argmax_fp32<<<ggrid, 256, 0, stream>>>(hazard, W, bias, rec);
        finalize_kernel<<<B_ROWS / 256, 256, 0, stream>>>(rec, labels, out_trunc, out_loss);
        scan_kernel_f32<<<B_ROWS, 256, 0, stream>>>(hazard, out_trunc, out_S);
    }
}